// Round 1
// baseline (113.884 us; speedup 1.0000x reference)
//
#include <hip/hip_runtime.h>

// CARAFE-style fused upsampler: B=8, C=64, H=W=128, scale=2, ks=3.
// out[b,c,Y,X] = sum_k softmax_k( g(y,x,k) / (d0^2+d1^2+0.5) ) * xpad[b,c,y+ki-1,x+kj-1]
// with (y,x) = (Y>>1, X>>1); offsets from 5x5 conv on nearest-upsampled channel mean.
//
// One block = one (batch, 16x16 low-res tile) -> 32x32 high-res outputs, all 64 ch.
// x is staged once in LDS (18x18 halo tile, 64 ch); mean tile derived in LDS.

#define TB 256

__global__ __launch_bounds__(256, 1) void carafe_fused(
    const float* __restrict__ x,
    const float* __restrict__ w_off,
    const float* __restrict__ b_off,
    float* __restrict__ out)
{
    constexpr int C = 64, H = 128, W = 128, HS = 256, WS = 256;

    __shared__ float xs[64][18][19];   // x tile, halo 1, stride 19 (bank mix)
    __shared__ float ms[18][19];       // channel-mean tile
    __shared__ float wc[50];           // conv weights [2][5][5] flat
    __shared__ float bc[2];

    const int tid = threadIdx.x;
    const int bid = blockIdx.x;
    const int b  = bid >> 6;
    const int ty = (bid >> 3) & 7;
    const int tx = bid & 7;
    const int y0 = ty * 16, x0 = tx * 16;

    if (tid < 50)      wc[tid] = w_off[tid];
    else if (tid < 52) bc[tid - 50] = b_off[tid - 50];

    // ---- stage x tile (zero-padded outside image) ----
    const float* xb = x + (size_t)b * C * H * W;
    for (int idx = tid; idx < 64 * 324; idx += TB) {
        const int c   = idx / 324;
        const int rem = idx - c * 324;
        const int r   = rem / 18;
        const int col = rem - r * 18;
        const int gy = y0 - 1 + r;
        const int gx = x0 - 1 + col;
        float v = 0.0f;
        if ((unsigned)gy < (unsigned)H && (unsigned)gx < (unsigned)W)
            v = xb[(c * H + gy) * W + gx];
        xs[c][r][col] = v;
    }
    __syncthreads();

    // ---- channel mean tile ----
    for (int idx = tid; idx < 324; idx += TB) {
        const int r = idx / 18, col = idx - r * 18;
        float s = 0.0f;
        #pragma unroll
        for (int c = 0; c < 64; ++c) s += xs[c][r][col];
        ms[r][col] = s * (1.0f / 64.0f);
    }
    __syncthreads();

    // ---- per-thread: 1x4 strip of high-res pixels ----
    const int hy = tid >> 3;            // 0..31 local high-res row
    const int hq = tid & 7;             // column group (4 px each)
    const int yr = hy >> 1;             // 0..15 local low-res row
    const int Yg = 2 * y0 + hy;
    const int Xg0 = 2 * x0 + hq * 4;

    float wgt[4][9];
    #pragma unroll
    for (int j = 0; j < 4; ++j) {
        const int lx = hq * 4 + j;      // local high-res col 0..31

        // 5x5 conv on mean_up: high-res tap (hy+p-2, lx+q-2) -> low-res floor-div.
        // Out-of-image taps land on zero-filled halo rows/cols of ms.
        float o0 = 0.0f, o1 = 0.0f;
        #pragma unroll
        for (int p = 0; p < 5; ++p) {
            const int mr = ((hy + p - 2) >> 1) + 1;
            #pragma unroll
            for (int q = 0; q < 5; ++q) {
                const int mc = ((lx + q - 2) >> 1) + 1;
                const float m = ms[mr][mc];
                o0 = fmaf(wc[p * 5 + q],      m, o0);
                o1 = fmaf(wc[25 + p * 5 + q], m, o1);
            }
        }
        const float off0 = tanhf(o0 + bc[0]) * 0.25f;   // /(2*scale)
        const float off1 = tanhf(o1 + bc[1]) * 0.25f;
        const float s0 = ((hy & 1) ? 0.25f : -0.25f) + off0;  // center + offset
        const float s1 = ((lx & 1) ? 0.25f : -0.25f) + off1;

        const int my = yr + 1, mxc = (lx >> 1) + 1;
        const float mctr = ms[my][mxc];

        float lg[9];
        float lmax = -1e30f;
        #pragma unroll
        for (int k = 0; k < 9; ++k) {
            const int di = k / 3 - 1, dj = k % 3 - 1;
            const float d0 = s0 - (float)di;
            const float d1 = s1 - (float)dj;
            const float kern = 1.0f / fmaf(d0, d0, fmaf(d1, d1, 0.5f));
            const float gd = ms[my + di][mxc + dj] - mctr;
            const float g  = 1.0f / fmaf(gd, gd, 1.0f);
            lg[k] = g * kern;
            lmax = fmaxf(lmax, lg[k]);
        }
        float ssum = 0.0f;
        #pragma unroll
        for (int k = 0; k < 9; ++k) { lg[k] = __expf(lg[k] - lmax); ssum += lg[k]; }
        const float inv = 1.0f / ssum;
        #pragma unroll
        for (int k = 0; k < 9; ++k) wgt[j][k] = lg[k] * inv;
    }

    // ---- CARAFE: 64 channels, 12 LDS taps shared by the 4 pixels ----
    const int xc0 = hq * 2;             // tap col base in xs (covers both low-res cols)
    float* ob = out + (size_t)b * C * HS * WS + (size_t)Yg * WS + Xg0;
    #pragma unroll 4
    for (int c = 0; c < 64; ++c) {
        float xv[3][4];
        #pragma unroll
        for (int di = 0; di < 3; ++di)
            #pragma unroll
            for (int dj = 0; dj < 4; ++dj)
                xv[di][dj] = xs[c][yr + di][xc0 + dj];
        float a[4];
        #pragma unroll
        for (int j = 0; j < 4; ++j) {
            const int px = j >> 1;
            float s = 0.0f;
            #pragma unroll
            for (int di = 0; di < 3; ++di)
                #pragma unroll
                for (int dj = 0; dj < 3; ++dj)
                    s = fmaf(wgt[j][di * 3 + dj], xv[di][px + dj], s);
            a[j] = s;
        }
        *reinterpret_cast<float4*>(ob + (size_t)c * HS * WS) =
            make_float4(a[0], a[1], a[2], a[3]);
    }
}

extern "C" void kernel_launch(void* const* d_in, const int* in_sizes, int n_in,
                              void* d_out, int out_size, void* d_ws, size_t ws_size,
                              hipStream_t stream) {
    const float* x  = (const float*)d_in[0];
    const float* w  = (const float*)d_in[1];
    const float* bo = (const float*)d_in[2];
    float* out = (float*)d_out;
    // grid: 8 batches * 8x8 tiles of 16x16 low-res
    carafe_fused<<<512, TB, 0, stream>>>(x, w, bo, out);
}

// Round 3
// 106.974 us; speedup vs baseline: 1.0646x; 1.0646x over previous
//
#include <hip/hip_runtime.h>

// CARAFE-style fused upsampler: B=8, C=64, H=W=128, scale=2, ks=3.
// K1 = channel mean -> d_ws; K2 = offsets/weights + CARAFE per
// (batch, 16x16 low-res tile, 32-channel group). LDS per K2 block ~45 KB ->
// 3 blocks/CU (12 waves/CU) vs the fused version's 89.6 KB -> 1 block/CU.

#define TB 256
#define CG 32   // channels per K2 block

__global__ __launch_bounds__(256) void mean_kernel(
    const float* __restrict__ x, float* __restrict__ mean)
{
    // one thread per pixel; B*H*W = 131072
    const int p = blockIdx.x * TB + threadIdx.x;
    const int b = p >> 14;            // H*W = 16384
    const int pix = p & 16383;
    const float* xb = x + ((size_t)b * 64) * 16384 + pix;
    float s = 0.0f;
    #pragma unroll
    for (int c = 0; c < 64; ++c) s += xb[(size_t)c * 16384];
    mean[p] = s * (1.0f / 64.0f);
}

__global__ __launch_bounds__(256, 3) void carafe_main(
    const float* __restrict__ x,
    const float* __restrict__ mean,
    const float* __restrict__ w_off,
    const float* __restrict__ b_off,
    float* __restrict__ out)
{
    constexpr int H = 128, W = 128, HS = 256, WS = 256;

    __shared__ float xs[CG][18][19];   // x tile (channel group), halo 1
    __shared__ float ms[18][19];       // mean tile
    __shared__ float wc[50];
    __shared__ float bc[2];

    const int tid = threadIdx.x;
    const int bid = blockIdx.x;
    // bid = b*128 + ty*16 + tx*2 + cg
    const int b  = bid >> 7;
    const int ty = (bid >> 4) & 7;
    const int tx = (bid >> 1) & 7;
    const int cg = bid & 1;
    const int y0 = ty * 16, x0 = tx * 16;
    const int c0 = cg * CG;

    if (tid < 50)      wc[tid] = w_off[tid];
    else if (tid < 52) bc[tid - 50] = b_off[tid - 50];

    // ---- stage mean tile (zero-padded outside image); 324 > TB -> loop! ----
    const float* mb = mean + (size_t)b * H * W;
    for (int idx = tid; idx < 324; idx += TB) {
        const int r = idx / 18, col = idx - r * 18;
        const int gy = y0 - 1 + r, gx = x0 - 1 + col;
        float v = 0.0f;
        if ((unsigned)gy < (unsigned)H && (unsigned)gx < (unsigned)W)
            v = mb[gy * W + gx];
        ms[r][col] = v;
    }

    // ---- stage x tile for this channel group ----
    const float* xb = x + ((size_t)b * 64 + c0) * (H * W);
    for (int idx = tid; idx < CG * 324; idx += TB) {
        const int c   = idx / 324;
        const int rem = idx - c * 324;
        const int r   = rem / 18;
        const int col = rem - r * 18;
        const int gy = y0 - 1 + r;
        const int gx = x0 - 1 + col;
        float v = 0.0f;
        if ((unsigned)gy < (unsigned)H && (unsigned)gx < (unsigned)W)
            v = xb[(c * H + gy) * W + gx];
        xs[c][r][col] = v;
    }
    __syncthreads();

    // ---- per-thread: 1x4 strip of high-res pixels ----
    const int hy = tid >> 3;            // 0..31 local high-res row
    const int hq = tid & 7;             // column group (4 px each)
    const int yr = hy >> 1;             // 0..15 local low-res row
    const int Yg = 2 * y0 + hy;
    const int Xg0 = 2 * x0 + hq * 4;

    float wgt[4][9];
    #pragma unroll
    for (int j = 0; j < 4; ++j) {
        const int lx = hq * 4 + j;      // local high-res col 0..31

        float o0 = 0.0f, o1 = 0.0f;
        #pragma unroll
        for (int p = 0; p < 5; ++p) {
            const int mr = ((hy + p - 2) >> 1) + 1;
            #pragma unroll
            for (int q = 0; q < 5; ++q) {
                const int mc = ((lx + q - 2) >> 1) + 1;
                const float m = ms[mr][mc];
                o0 = fmaf(wc[p * 5 + q],      m, o0);
                o1 = fmaf(wc[25 + p * 5 + q], m, o1);
            }
        }
        const float off0 = tanhf(o0 + bc[0]) * 0.25f;
        const float off1 = tanhf(o1 + bc[1]) * 0.25f;
        const float s0 = ((hy & 1) ? 0.25f : -0.25f) + off0;
        const float s1 = ((lx & 1) ? 0.25f : -0.25f) + off1;

        const int my = yr + 1, mxc = (lx >> 1) + 1;
        const float mctr = ms[my][mxc];

        float lg[9];
        float lmax = -1e30f;
        #pragma unroll
        for (int k = 0; k < 9; ++k) {
            const int di = k / 3 - 1, dj = k % 3 - 1;
            const float d0 = s0 - (float)di;
            const float d1 = s1 - (float)dj;
            const float kern = 1.0f / fmaf(d0, d0, fmaf(d1, d1, 0.5f));
            const float gd = ms[my + di][mxc + dj] - mctr;
            const float g  = 1.0f / fmaf(gd, gd, 1.0f);
            lg[k] = g * kern;
            lmax = fmaxf(lmax, lg[k]);
        }
        float ssum = 0.0f;
        #pragma unroll
        for (int k = 0; k < 9; ++k) { lg[k] = __expf(lg[k] - lmax); ssum += lg[k]; }
        const float inv = 1.0f / ssum;
        #pragma unroll
        for (int k = 0; k < 9; ++k) wgt[j][k] = lg[k] * inv;
    }

    // ---- CARAFE over this block's channels ----
    const int xc0 = hq * 2;
    float* ob = out + ((size_t)b * 64 + c0) * HS * WS + (size_t)Yg * WS + Xg0;
    #pragma unroll 4
    for (int c = 0; c < CG; ++c) {
        float xv[3][4];
        #pragma unroll
        for (int di = 0; di < 3; ++di)
            #pragma unroll
            for (int dj = 0; dj < 4; ++dj)
                xv[di][dj] = xs[c][yr + di][xc0 + dj];
        float a[4];
        #pragma unroll
        for (int j = 0; j < 4; ++j) {
            const int px = j >> 1;
            float s = 0.0f;
            #pragma unroll
            for (int di = 0; di < 3; ++di)
                #pragma unroll
                for (int dj = 0; dj < 3; ++dj)
                    s = fmaf(wgt[j][di * 3 + dj], xv[di][px + dj], s);
            a[j] = s;
        }
        *reinterpret_cast<float4*>(ob + (size_t)c * HS * WS) =
            make_float4(a[0], a[1], a[2], a[3]);
    }
}

extern "C" void kernel_launch(void* const* d_in, const int* in_sizes, int n_in,
                              void* d_out, int out_size, void* d_ws, size_t ws_size,
                              hipStream_t stream) {
    const float* x  = (const float*)d_in[0];
    const float* w  = (const float*)d_in[1];
    const float* bo = (const float*)d_in[2];
    float* out  = (float*)d_out;
    float* mean = (float*)d_ws;            // 8*128*128 floats = 512 KB

    mean_kernel<<<512, TB, 0, stream>>>(x, mean);
    // grid: 8 batches * 8x8 tiles * 2 channel groups
    carafe_main<<<1024, TB, 0, stream>>>(x, mean, w, bo, out);
}